// Round 2
// baseline (1295.543 us; speedup 1.0000x reference)
//
#include <hip/hip_runtime.h>
#include <hip/hip_bf16.h>

#define D_MODEL 1280
#define NUM_HEADS 16
#define D_K 80
#define SEQ 1024
#define BATCH 4

typedef __hip_bfloat16 bf16;

__device__ __forceinline__ float b2f(bf16 x) { return __bfloat162float(x); }
__device__ __forceinline__ bf16 f2b(float x) { return __float2bfloat16(x); }

// ---------------------------------------------------------------------------
// Kernel 1: channel shuffle + per-head QKV projection. Inputs fp32.
// grid (B*S/32, H), 256 threads. Threads 0..239 each own one output row
// (which in {q,k,v}, e in 0..79) and keep the 80 weights in registers.
// Q/K/V stored bf16 in ws.
// ---------------------------------------------------------------------------
__global__ __launch_bounds__(256) void qkv_kernel(
    const float* __restrict__ src,
    const float* __restrict__ Wq, const float* __restrict__ bq,
    const float* __restrict__ Wk, const float* __restrict__ bk,
    const float* __restrict__ Wv, const float* __restrict__ bv,
    bf16* __restrict__ Qb, bf16* __restrict__ Kb, bf16* __restrict__ Vb)
{
    __shared__ float xh[32 * 80];
    const int h = blockIdx.y;
    const int b = blockIdx.x >> 5;            // S/32 = 32 tiles per batch
    const int s0 = (blockIdx.x & 31) * 32;
    const int tid = threadIdx.x;

    // stage shuffled per-head input tile: xh[i][d] = src[b, s0+i, perm(h*80+d)]
    // perm(j) = (j%5)*256 + j/5   (channel shuffle inverse gather)
    for (int idx = tid; idx < 32 * 80; idx += 256) {
        int i = idx / 80, d = idx % 80;
        int j = h * 80 + d;
        int ps = (j % 5) * 256 + (j / 5);
        xh[idx] = src[(size_t)(b * SEQ + s0 + i) * D_MODEL + ps];
    }
    __syncthreads();

    if (tid < 240) {
        const int which = tid / 80;           // 0=q 1=k 2=v
        const int e = tid % 80;
        const float* W  = (which == 0) ? Wq : (which == 1) ? Wk : Wv;
        const float* Bi = (which == 0) ? bq : (which == 1) ? bk : bv;
        bf16* Out       = (which == 0) ? Qb : (which == 1) ? Kb : Vb;

        // load weight row into registers (80 floats = 20 float4)
        const float4* wr = (const float4*)(W + (size_t)(h * 80 + e) * 80);
        float w[80];
        #pragma unroll
        for (int u = 0; u < 20; u++) {
            float4 x = wr[u];
            w[4 * u]     = x.x;
            w[4 * u + 1] = x.y;
            w[4 * u + 2] = x.z;
            w[4 * u + 3] = x.w;
        }
        const float bias = Bi[h * 80 + e];
        const float4* xh4 = (const float4*)xh;

        for (int i = 0; i < 32; i++) {
            float acc = bias;
            #pragma unroll
            for (int d4 = 0; d4 < 20; d4++) {
                float4 xv = xh4[i * 20 + d4];
                acc += xv.x * w[d4 * 4] + xv.y * w[d4 * 4 + 1] +
                       xv.z * w[d4 * 4 + 2] + xv.w * w[d4 * 4 + 3];
            }
            Out[(size_t)((b * NUM_HEADS + h) * SEQ + s0 + i) * D_K + e] = f2b(acc);
        }
    }
}

// ---------------------------------------------------------------------------
// Kernel 2: flash attention per (b,h). grid (S/32, B*H), 256 threads.
// Q-tile = 32 queries, K-tiles of 64, online softmax. Thread t owns queries
// {2*(t&15), 2*(t&15)+1} and dims (t>>4)*5..+5 of the output accumulator.
// LDS rows padded (81 / 66) to avoid power-of-2 bank strides.
// ---------------------------------------------------------------------------
__global__ __launch_bounds__(256) void attn_kernel(
    const bf16* __restrict__ Qb, const bf16* __restrict__ Kb,
    const bf16* __restrict__ Vb, float* __restrict__ Cc)
{
    __shared__ float Qt[32 * 81];
    __shared__ float Kt[64 * 81];
    __shared__ float Vt[64 * 80];
    __shared__ float P[32 * 66];
    __shared__ float mrow[32], lrow[32], arow[32];

    const int bh = blockIdx.y;                // b*H + h
    const int s0 = blockIdx.x * 32;
    const int b = bh / NUM_HEADS, h = bh % NUM_HEADS;
    const int tid = threadIdx.x;
    const size_t base = (size_t)bh * SEQ * D_K;

    for (int idx = tid; idx < 32 * 80; idx += 256) {
        int q = idx / 80, d = idx % 80;
        Qt[q * 81 + d] = b2f(Qb[base + (size_t)(s0 + q) * D_K + d]);
    }
    if (tid < 32) { mrow[tid] = -1e30f; lrow[tid] = 0.f; }

    const int qi2 = tid & 15;
    const int eb  = tid >> 4;                 // 0..15
    const int q0 = qi2 * 2, q1 = q0 + 1;
    const int k0 = eb * 4;
    float accO[2][5] = {{0.f}};
    const float scale = 0.11180339887498949f; // 1/sqrt(80)

    for (int kt = 0; kt < 16; kt++) {
        __syncthreads();
        for (int idx = tid; idx < 64 * 80; idx += 256) {
            int j = idx / 80, d = idx % 80;
            size_t g = base + (size_t)(kt * 64 + j) * D_K + d;
            Kt[j * 81 + d] = b2f(Kb[g]);
            Vt[j * 80 + d] = b2f(Vb[g]);
        }
        __syncthreads();

        // scores: 2 queries x 4 keys per thread, dot over 80
        float sc[2][4] = {{0.f}};
        for (int d = 0; d < 80; d++) {
            float a0 = Qt[q0 * 81 + d];
            float a1 = Qt[q1 * 81 + d];
            #pragma unroll
            for (int kk = 0; kk < 4; kk++) {
                float kv = Kt[(k0 + kk) * 81 + d];
                sc[0][kk] += a0 * kv;
                sc[1][kk] += a1 * kv;
            }
        }
        #pragma unroll
        for (int kk = 0; kk < 4; kk++) {
            P[q0 * 66 + k0 + kk] = sc[0][kk] * scale;
            P[q1 * 66 + k0 + kk] = sc[1][kk] * scale;
        }
        __syncthreads();

        // online-softmax row statistics (32 rows, one thread each)
        if (tid < 32) {
            float m_old = mrow[tid];
            float m_new = m_old;
            for (int j = 0; j < 64; j++) m_new = fmaxf(m_new, P[tid * 66 + j]);
            float al = __expf(m_old - m_new);   // first tile: 0
            float s = 0.f;
            for (int j = 0; j < 64; j++) {
                float p = __expf(P[tid * 66 + j] - m_new);
                P[tid * 66 + j] = p;
                s += p;
            }
            mrow[tid] = m_new;
            lrow[tid] = lrow[tid] * al + s;
            arow[tid] = al;
        }
        __syncthreads();

        // O = O*alpha + P @ V
        float a0 = arow[q0], a1 = arow[q1];
        #pragma unroll
        for (int c = 0; c < 5; c++) { accO[0][c] *= a0; accO[1][c] *= a1; }
        for (int j = 0; j < 64; j++) {
            float p0 = P[q0 * 66 + j], p1 = P[q1 * 66 + j];
            #pragma unroll
            for (int c = 0; c < 5; c++) {
                float v = Vt[j * 80 + eb * 5 + c];
                accO[0][c] += p0 * v;
                accO[1][c] += p1 * v;
            }
        }
    }
    __syncthreads();

    float il0 = 1.f / lrow[q0], il1 = 1.f / lrow[q1];
    #pragma unroll
    for (int c = 0; c < 5; c++) {
        int e = h * D_K + eb * 5 + c;
        Cc[(size_t)(b * SEQ + s0 + q0) * D_MODEL + e] = accO[0][c] * il0;
        Cc[(size_t)(b * SEQ + s0 + q1) * D_MODEL + e] = accO[1][c] * il1;
    }
}

// ---------------------------------------------------------------------------
// Kernel 3: output projection out = Cc @ Wo^T + bo. fp32 in/out.
// grid (4096/32, 1280/128), 256 threads, 4x4 register tile, k-chunks of 64.
// ---------------------------------------------------------------------------
__global__ __launch_bounds__(256) void proj_kernel(
    const float* __restrict__ Cc, const float* __restrict__ Wo,
    const float* __restrict__ bo, float* __restrict__ out)
{
    __shared__ float Xs[32 * 65];
    __shared__ float Ws[128 * 65];
    const int t0 = blockIdx.x * 32;
    const int o0 = blockIdx.y * 128;
    const int tid = threadIdx.x;
    const int to = tid & 7;       // token group: tokens to*4..+3
    const int oo = tid >> 3;      // 0..31: outputs oo*4..+3
    float acc[4][4] = {{0.f}};

    for (int kc = 0; kc < 20; kc++) {
        __syncthreads();
        for (int idx = tid; idx < 32 * 64; idx += 256) {
            int i = idx >> 6, kk = idx & 63;
            Xs[i * 65 + kk] = Cc[(size_t)(t0 + i) * D_MODEL + kc * 64 + kk];
        }
        for (int idx = tid; idx < 128 * 64; idx += 256) {
            int o = idx >> 6, kk = idx & 63;
            Ws[o * 65 + kk] = Wo[(size_t)(o0 + o) * D_MODEL + kc * 64 + kk];
        }
        __syncthreads();
        for (int k = 0; k < 64; k++) {
            float xr[4], wr[4];
            #pragma unroll
            for (int ii = 0; ii < 4; ii++) xr[ii] = Xs[(to * 4 + ii) * 65 + k];
            #pragma unroll
            for (int jj = 0; jj < 4; jj++) wr[jj] = Ws[(oo * 4 + jj) * 65 + k];
            #pragma unroll
            for (int ii = 0; ii < 4; ii++)
                #pragma unroll
                for (int jj = 0; jj < 4; jj++)
                    acc[ii][jj] += xr[ii] * wr[jj];
        }
    }

    #pragma unroll
    for (int jj = 0; jj < 4; jj++) {
        float bv = bo[o0 + oo * 4 + jj];
        #pragma unroll
        for (int ii = 0; ii < 4; ii++) {
            out[(size_t)(t0 + to * 4 + ii) * D_MODEL + o0 + oo * 4 + jj] =
                acc[ii][jj] + bv;
        }
    }
}

// ---------------------------------------------------------------------------
extern "C" void kernel_launch(void* const* d_in, const int* in_sizes, int n_in,
                              void* d_out, int out_size, void* d_ws, size_t ws_size,
                              hipStream_t stream) {
    const float* src = (const float*)d_in[0];
    // d_in[1] (k) and d_in[2] (v) are ignored by the reference.
    const float* Wq = (const float*)d_in[3];
    const float* bq = (const float*)d_in[4];
    const float* Wk = (const float*)d_in[5];
    const float* bk = (const float*)d_in[6];
    const float* Wv = (const float*)d_in[7];
    const float* bv = (const float*)d_in[8];
    const float* Wo = (const float*)d_in[9];
    const float* bo = (const float*)d_in[10];
    float* out = (float*)d_out;

    // workspace layout (bytes):
    //   Qb bf16 [B,H,S,80]  @ 0        (10 MB)
    //   Kb bf16             @ 10 MB
    //   Vb bf16             @ 20 MB
    //   Cc fp32 [B,S,1280]  @ 30 MB    (20 MB)   -> total 50 MB
    char* ws = (char*)d_ws;
    bf16* Qb = (bf16*)(ws);
    bf16* Kb = (bf16*)(ws + (size_t)10485760);
    bf16* Vb = (bf16*)(ws + (size_t)20971520);
    float* Cc = (float*)(ws + (size_t)31457280);

    qkv_kernel<<<dim3(BATCH * SEQ / 32, NUM_HEADS), 256, 0, stream>>>(
        src, Wq, bq, Wk, bk, Wv, bv, Qb, Kb, Vb);
    attn_kernel<<<dim3(SEQ / 32, BATCH * NUM_HEADS), 256, 0, stream>>>(
        Qb, Kb, Vb, Cc);
    proj_kernel<<<dim3(BATCH * SEQ / 32, D_MODEL / 128), 256, 0, stream>>>(
        Cc, Wo, bo, out);
}

// Round 3
// 263.206 us; speedup vs baseline: 4.9222x; 4.9222x over previous
//
#include <hip/hip_runtime.h>
#include <hip/hip_bf16.h>

#define D_MODEL 1280
#define NUM_HEADS 16
#define D_K 80
#define DP 96            // head dim padded to 3*32 for MFMA K-steps
#define SEQ 1024
#define BATCH 4
#define BH (BATCH*NUM_HEADS)

typedef __hip_bfloat16 bf16;
typedef short short8 __attribute__((ext_vector_type(8)));
typedef float f32x4 __attribute__((ext_vector_type(4)));

__device__ __forceinline__ float b2f(bf16 x) { return __bfloat162float(x); }
__device__ __forceinline__ bf16 f2b(float x) { return __float2bfloat16(x); }

#define MFMA16(a, b, c) __builtin_amdgcn_mfma_f32_16x16x32_bf16(a, b, c, 0, 0, 0)

// ---------------------------------------------------------------------------
// Kernel 1: channel shuffle + per-head QKV projection (fp32 in, bf16 out).
// Q scaled by (1/sqrt(80))*log2(e) so attention can use exp2 directly.
// Q,K written padded to 96 dims (zeros); V written transposed [bh][e][s].
// grid (B*S/32, H), 256 threads.
// ---------------------------------------------------------------------------
__global__ __launch_bounds__(256) void qkv_kernel(
    const float* __restrict__ src,
    const float* __restrict__ Wq, const float* __restrict__ bq,
    const float* __restrict__ Wk, const float* __restrict__ bk,
    const float* __restrict__ Wv, const float* __restrict__ bv,
    bf16* __restrict__ Qb, bf16* __restrict__ Kb, bf16* __restrict__ Vg)
{
    __shared__ float xh[32 * 80];
    const int h = blockIdx.y;
    const int b = blockIdx.x >> 5;
    const int s0 = (blockIdx.x & 31) * 32;
    const int tid = threadIdx.x;
    const int bh = b * NUM_HEADS + h;

    for (int idx = tid; idx < 32 * 80; idx += 256) {
        int i = idx / 80, d = idx % 80;
        int j = h * 80 + d;
        int ps = (j % 5) * 256 + (j / 5);     // channel-shuffle gather
        xh[idx] = src[(size_t)(b * SEQ + s0 + i) * D_MODEL + ps];
    }
    __syncthreads();

    if (tid < 240) {
        const int which = tid / 80;           // 0=q 1=k 2=v
        const int e = tid % 80;
        const float* W  = (which == 0) ? Wq : (which == 1) ? Wk : Wv;
        const float* Bi = (which == 0) ? bq : (which == 1) ? bk : bv;

        const float4* wr = (const float4*)(W + (size_t)(h * 80 + e) * 80);
        float w[80];
        #pragma unroll
        for (int u = 0; u < 20; u++) {
            float4 x = wr[u];
            w[4*u] = x.x; w[4*u+1] = x.y; w[4*u+2] = x.z; w[4*u+3] = x.w;
        }
        const float bias = Bi[h * 80 + e];
        const float4* xh4 = (const float4*)xh;
        const float qscale = 1.4426950408889634f * 0.11180339887498949f;

        for (int i = 0; i < 32; i++) {
            float acc = bias;
            #pragma unroll
            for (int d4 = 0; d4 < 20; d4++) {
                float4 xv = xh4[i * 20 + d4];
                acc += xv.x * w[d4*4] + xv.y * w[d4*4+1] +
                       xv.z * w[d4*4+2] + xv.w * w[d4*4+3];
            }
            if (which == 0)
                Qb[(size_t)(bh * SEQ + s0 + i) * DP + e] = f2b(acc * qscale);
            else if (which == 1)
                Kb[(size_t)(bh * SEQ + s0 + i) * DP + e] = f2b(acc);
            else
                Vg[((size_t)bh * D_K + e) * SEQ + s0 + i] = f2b(acc);
        }
    } else {
        // zero-fill the d=80..95 pad of Q and K
        int p = tid - 240;                    // 0..15
        for (int i = 0; i < 32; i++) {
            size_t row = (size_t)(bh * SEQ + s0 + i) * DP;
            Qb[row + 80 + p] = f2b(0.f);
            Kb[row + 80 + p] = f2b(0.f);
        }
    }
}

// ---------------------------------------------------------------------------
// Kernel 2: MFMA flash attention. grid (S/128, BH), 256 threads = 4 waves.
// Block: 128 queries; wave: 32 queries. K-tiles of 64 keys.
// S^T = K·Q^T via mfma_16x16x32 (A=K rows, B=Q rows) so each lane's scores
// share one q-column -> softmax stats = in-lane reduce + shfl_xor(16,32).
// P -> LDS (A-layout) -> PV with V^T tile. Q LDS reused as P region.
// ---------------------------------------------------------------------------
__global__ __launch_bounds__(256) void attn_kernel(
    const bf16* __restrict__ Qb, const bf16* __restrict__ Kb,
    const bf16* __restrict__ Vg, bf16* __restrict__ Cc)
{
    __shared__ char smem[48384];          // Qs/P 24576 | Ks 12288 | Vt 11520
    bf16* Qs = (bf16*)smem;
    bf16* Ks = (bf16*)(smem + 24576);
    bf16* Vt = (bf16*)(smem + 36864);

    const int tid = threadIdx.x;
    const int wave = tid >> 6, lane = tid & 63;
    const int lquad = lane >> 4, lcol = lane & 15;
    const int bh = blockIdx.y;
    const int b = bh >> 4, h = bh & 15;
    const int q0 = blockIdx.x * 128;

    // stage Q tile: 128 x 96 bf16, contiguous in global
    {
        const uint4* sg = (const uint4*)(Qb + (size_t)(bh * SEQ + q0) * DP);
        uint4* dl = (uint4*)Qs;
        #pragma unroll
        for (int i = 0; i < 6; i++) dl[tid + i * 256] = sg[tid + i * 256];
    }
    __syncthreads();

    // preload Q as B-fragments (lane: q-row = 32*wave + nt*16 + lcol, d-chunk quad*8)
    short8 qf[2][3];
    #pragma unroll
    for (int nt = 0; nt < 2; nt++)
        #pragma unroll
        for (int ks = 0; ks < 3; ks++)
            qf[nt][ks] = *(const short8*)(Qs + (wave*32 + nt*16 + lcol)*DP + ks*32 + lquad*8);

    f32x4 Oacc[2][5];
    #pragma unroll
    for (int mt = 0; mt < 2; mt++)
        #pragma unroll
        for (int ne = 0; ne < 5; ne++)
            #pragma unroll
            for (int r = 0; r < 4; r++) Oacc[mt][ne][r] = 0.f;

    float m[2] = {-1e30f, -1e30f}, l[2] = {0.f, 0.f};
    bf16* Pw = (bf16*)(smem + wave * 4608);   // per-wave 32 x 72 bf16 (overlaps Qs)

    for (int kt = 0; kt < 16; kt++) {
        __syncthreads();
        // stage K tile: 64 x 96 contiguous
        {
            const uint4* sg = (const uint4*)(Kb + (size_t)(bh * SEQ + kt * 64) * DP);
            uint4* dl = (uint4*)Ks;
            #pragma unroll
            for (int i = 0; i < 3; i++) dl[tid + i * 256] = sg[tid + i * 256];
        }
        // stage V^T tile: Vt[e][0..63] <- Vg[bh][e][kt*64+..], rows padded to 72
        #pragma unroll
        for (int i = 0; i < 3; i++) {
            int idx = tid + i * 256;
            if (idx < 640) {
                int e = idx >> 3, c = idx & 7;
                *(uint4*)(Vt + e * 72 + c * 8) =
                    *(const uint4*)(Vg + ((size_t)(bh * D_K + e) << 10) + kt * 64 + c * 8);
            }
        }
        __syncthreads();

        // S^T tiles: D[k-row][q-col], 4 mtiles(k) x 2 ntiles(q) x 3 ksteps(d)
        f32x4 st[4][2];
        #pragma unroll
        for (int mt = 0; mt < 4; mt++)
            #pragma unroll
            for (int nt = 0; nt < 2; nt++)
                #pragma unroll
                for (int r = 0; r < 4; r++) st[mt][nt][r] = 0.f;

        #pragma unroll
        for (int ks = 0; ks < 3; ks++) {
            #pragma unroll
            for (int mt = 0; mt < 4; mt++) {
                short8 af = *(const short8*)(Ks + (mt*16 + lcol)*DP + ks*32 + lquad*8);
                st[mt][0] = MFMA16(af, qf[0][ks], st[mt][0]);
                st[mt][1] = MFMA16(af, qf[1][ks], st[mt][1]);
            }
        }

        // online softmax over k for each q-column (scores pre-scaled by log2e/sqrt(dk))
        float a[2];
        #pragma unroll
        for (int nt = 0; nt < 2; nt++) {
            float mx = st[0][nt][0];
            #pragma unroll
            for (int mt = 0; mt < 4; mt++)
                #pragma unroll
                for (int r = 0; r < 4; r++) mx = fmaxf(mx, st[mt][nt][r]);
            mx = fmaxf(mx, __shfl_xor(mx, 16));
            mx = fmaxf(mx, __shfl_xor(mx, 32));
            float mn = fmaxf(m[nt], mx);
            a[nt] = exp2f(m[nt] - mn);
            m[nt] = mn;
            float s = 0.f;
            #pragma unroll
            for (int mt = 0; mt < 4; mt++)
                #pragma unroll
                for (int r = 0; r < 4; r++) {
                    float p = exp2f(st[mt][nt][r] - mn);
                    s += p;
                    // P[q_local][k_local], q_local = nt*16+lcol, k_local = mt*16+quad*4+r
                    Pw[(nt*16 + lcol)*72 + mt*16 + lquad*4 + r] = f2b(p);
                }
            s += __shfl_xor(s, 16);
            s += __shfl_xor(s, 32);
            l[nt] = l[nt] * a[nt] + s;
        }

        // rescale O accumulators: O rows q_local = mt*16 + quad*4 + r
        #pragma unroll
        for (int mt = 0; mt < 2; mt++) {
            f32x4 aq;
            #pragma unroll
            for (int r = 0; r < 4; r++)
                aq[r] = __shfl(a[mt], (lane & 48) | (lquad*4 + r));
            #pragma unroll
            for (int ne = 0; ne < 5; ne++)
                #pragma unroll
                for (int r = 0; r < 4; r++) Oacc[mt][ne][r] *= aq[r];
        }

        // PV: O[q][e] += P[q][j] V[j][e]; A from Pw, B from Vt
        #pragma unroll
        for (int js = 0; js < 2; js++) {
            short8 pf[2];
            #pragma unroll
            for (int mt = 0; mt < 2; mt++)
                pf[mt] = *(const short8*)(Pw + (mt*16 + lcol)*72 + js*32 + lquad*8);
            #pragma unroll
            for (int ne = 0; ne < 5; ne++) {
                short8 vf = *(const short8*)(Vt + (ne*16 + lcol)*72 + js*32 + lquad*8);
                Oacc[0][ne] = MFMA16(pf[0], vf, Oacc[0][ne]);
                Oacc[1][ne] = MFMA16(pf[1], vf, Oacc[1][ne]);
            }
        }
    }

    // epilogue: normalize by 1/l and write concat layout Cc[b][s][h*80+e] (bf16)
    float inv[2] = {1.f / l[0], 1.f / l[1]};
    #pragma unroll
    for (int mt = 0; mt < 2; mt++) {
        f32x4 li;
        #pragma unroll
        for (int r = 0; r < 4; r++)
            li[r] = __shfl(inv[mt], (lane & 48) | (lquad*4 + r));
        #pragma unroll
        for (int ne = 0; ne < 5; ne++)
            #pragma unroll
            for (int r = 0; r < 4; r++) {
                int s_row = q0 + wave*32 + mt*16 + lquad*4 + r;
                int e = ne*16 + lcol;
                Cc[(size_t)(b * SEQ + s_row) * D_MODEL + h * D_K + e] =
                    f2b(Oacc[mt][ne][r] * li[r]);
            }
    }
}

// ---------------------------------------------------------------------------
// Kernel 3a: Wo fp32 -> bf16 one-shot convert.
// ---------------------------------------------------------------------------
__global__ __launch_bounds__(256) void cvt_kernel(
    const float* __restrict__ Wo, bf16* __restrict__ Wb)
{
    int idx = (blockIdx.x * 256 + threadIdx.x) * 4;
    float4 v = *(const float4*)(Wo + idx);
    Wb[idx]     = f2b(v.x);
    Wb[idx + 1] = f2b(v.y);
    Wb[idx + 2] = f2b(v.z);
    Wb[idx + 3] = f2b(v.w);
}

// ---------------------------------------------------------------------------
// Kernel 3b: output projection out = Cc @ Wo^T + bo via MFMA (m97 pattern).
// grid (4096/128, 1280/128), 256 threads = 4 waves in 2x2; BK=64.
// ---------------------------------------------------------------------------
__global__ __launch_bounds__(256) void proj_kernel(
    const bf16* __restrict__ Cc, const bf16* __restrict__ Wb,
    const float* __restrict__ bo, float* __restrict__ out)
{
    __shared__ bf16 As[128 * 72];
    __shared__ bf16 Bs[128 * 72];
    const int tid = threadIdx.x;
    const int wave = tid >> 6, lane = tid & 63;
    const int lquad = lane >> 4, lcol = lane & 15;
    const int t0 = blockIdx.x * 128, o0 = blockIdx.y * 128;
    const int mrow = (wave & 1) * 64, ncol = (wave >> 1) * 64;

    f32x4 acc[4][4];
    #pragma unroll
    for (int mt = 0; mt < 4; mt++)
        #pragma unroll
        for (int nt = 0; nt < 4; nt++)
            #pragma unroll
            for (int r = 0; r < 4; r++) acc[mt][nt][r] = 0.f;

    for (int kc = 0; kc < 20; kc++) {
        __syncthreads();
        #pragma unroll
        for (int i = 0; i < 4; i++) {
            int idx = tid + i * 256;
            int r = idx >> 3, c = idx & 7;
            *(uint4*)(As + r * 72 + c * 8) =
                *(const uint4*)(Cc + (size_t)(t0 + r) * D_MODEL + kc * 64 + c * 8);
            *(uint4*)(Bs + r * 72 + c * 8) =
                *(const uint4*)(Wb + (size_t)(o0 + r) * D_MODEL + kc * 64 + c * 8);
        }
        __syncthreads();
        #pragma unroll
        for (int ks = 0; ks < 2; ks++) {
            short8 am[4], bn[4];
            #pragma unroll
            for (int t = 0; t < 4; t++) {
                am[t] = *(const short8*)(As + (mrow + t*16 + lcol)*72 + ks*32 + lquad*8);
                bn[t] = *(const short8*)(Bs + (ncol + t*16 + lcol)*72 + ks*32 + lquad*8);
            }
            #pragma unroll
            for (int mt = 0; mt < 4; mt++)
                #pragma unroll
                for (int nt = 0; nt < 4; nt++)
                    acc[mt][nt] = MFMA16(am[mt], bn[nt], acc[mt][nt]);
        }
    }

    #pragma unroll
    for (int nt = 0; nt < 4; nt++) {
        float bias = bo[o0 + ncol + nt*16 + lcol];
        #pragma unroll
        for (int mt = 0; mt < 4; mt++)
            #pragma unroll
            for (int r = 0; r < 4; r++)
                out[(size_t)(t0 + mrow + mt*16 + lquad*4 + r) * D_MODEL
                    + o0 + ncol + nt*16 + lcol] = acc[mt][nt][r] + bias;
    }
}

// ---------------------------------------------------------------------------
extern "C" void kernel_launch(void* const* d_in, const int* in_sizes, int n_in,
                              void* d_out, int out_size, void* d_ws, size_t ws_size,
                              hipStream_t stream) {
    const float* src = (const float*)d_in[0];
    const float* Wq = (const float*)d_in[3];
    const float* bq = (const float*)d_in[4];
    const float* Wk = (const float*)d_in[5];
    const float* bk = (const float*)d_in[6];
    const float* Wv = (const float*)d_in[7];
    const float* bv = (const float*)d_in[8];
    const float* Wo = (const float*)d_in[9];
    const float* bo = (const float*)d_in[10];
    float* out = (float*)d_out;

    // ws layout (bytes):
    //   Qb bf16 [BH][S][96]   @ 0         12,582,912
    //   Kb bf16 [BH][S][96]   @ 12582912  12,582,912
    //   Vg bf16 [BH][80][S]   @ 25165824  10,485,760
    //   Cc bf16 [B][S][1280]  @ 35651584  10,485,760
    //   Wb bf16 [1280][1280]  @ 46137344   3,276,800   (total 49,414,144)
    char* ws = (char*)d_ws;
    bf16* Qb = (bf16*)(ws);
    bf16* Kb = (bf16*)(ws + (size_t)12582912);
    bf16* Vg = (bf16*)(ws + (size_t)25165824);
    bf16* Cc = (bf16*)(ws + (size_t)35651584);
    bf16* Wb = (bf16*)(ws + (size_t)46137344);

    qkv_kernel<<<dim3(BATCH * SEQ / 32, NUM_HEADS), 256, 0, stream>>>(
        src, Wq, bq, Wk, bk, Wv, bv, Qb, Kb, Vg);
    cvt_kernel<<<dim3(D_MODEL * D_MODEL / 1024), 256, 0, stream>>>(Wo, Wb);
    attn_kernel<<<dim3(SEQ / 128, BH), 256, 0, stream>>>(Qb, Kb, Vg, Cc);
    proj_kernel<<<dim3(SEQ * BATCH / 128, D_MODEL / 128), 256, 0, stream>>>(
        Cc, Wb, bo, out);
}

// Round 4
// 216.750 us; speedup vs baseline: 5.9771x; 1.2143x over previous
//
#include <hip/hip_runtime.h>
#include <hip/hip_bf16.h>

#define D_MODEL 1280
#define NUM_HEADS 16
#define D_K 80
#define DP 96            // head dim padded to 3*32 for MFMA K-steps
#define SEQ 1024
#define BATCH 4
#define BH (BATCH*NUM_HEADS)

typedef __hip_bfloat16 bf16;
typedef short short8 __attribute__((ext_vector_type(8)));
typedef float f32x4 __attribute__((ext_vector_type(4)));

__device__ __forceinline__ float b2f(bf16 x) { return __bfloat162float(x); }
__device__ __forceinline__ bf16 f2b(float x) { return __float2bfloat16(x); }

#define MFMA16(a, b, c) __builtin_amdgcn_mfma_f32_16x16x32_bf16(a, b, c, 0, 0, 0)

// ---------------------------------------------------------------------------
// Kernel 0a: pack Wq|Wk|Wv -> Wcat[h][240][96] bf16, zero-padded K dim.
// 16*240*96 = 368640 elements = 1440 blocks * 256.
// ---------------------------------------------------------------------------
__global__ __launch_bounds__(256) void cvtw_kernel(
    const float* __restrict__ Wq, const float* __restrict__ Wk,
    const float* __restrict__ Wv, bf16* __restrict__ Wcat)
{
    int idx = blockIdx.x * 256 + threadIdx.x;
    int col = idx % 96;
    int row = (idx / 96) % 240;
    int h   = idx / (96 * 240);
    int mat = row / 80, e = row % 80;
    const float* W = (mat == 0) ? Wq : (mat == 1) ? Wk : Wv;
    float v = (col < 80) ? W[(size_t)(h * 80 + e) * 80 + col] : 0.f;
    Wcat[idx] = f2b(v);
}

// ---------------------------------------------------------------------------
// Kernel 0b: Wo fp32 -> bf16 one-shot convert.
// ---------------------------------------------------------------------------
__global__ __launch_bounds__(256) void cvt_kernel(
    const float* __restrict__ Wo, bf16* __restrict__ Wb)
{
    int idx = (blockIdx.x * 256 + threadIdx.x) * 4;
    float4 v = *(const float4*)(Wo + idx);
    Wb[idx]     = f2b(v.x);
    Wb[idx + 1] = f2b(v.y);
    Wb[idx + 2] = f2b(v.z);
    Wb[idx + 3] = f2b(v.w);
}

// ---------------------------------------------------------------------------
// Kernel 1: channel shuffle + per-head QKV projection via MFMA.
// grid (B*S/128, H), 256 threads = 4 waves; wave owns 32 tokens.
// X staged in LDS (bf16, row stride 104: 2-way-free bank pattern);
// W fragments loaded per-lane from global Wcat (L2-resident, 45 KB/head).
// Q/K: A=X,B=W -> row=token. V: A=W,B=X -> row=e (coalesced V^T write).
// ---------------------------------------------------------------------------
__global__ __launch_bounds__(256) void qkv_kernel(
    const float* __restrict__ src,
    const float* __restrict__ bq, const float* __restrict__ bk,
    const float* __restrict__ bv, const bf16* __restrict__ Wcat,
    bf16* __restrict__ Qb, bf16* __restrict__ Kb, bf16* __restrict__ Vg)
{
    __shared__ bf16 Xs[128 * 104];
    const int h = blockIdx.y;
    const int b = blockIdx.x >> 3;            // 8 tiles of 128 per batch
    const int s0 = (blockIdx.x & 7) * 128;
    const int tid = threadIdx.x;
    const int wave = tid >> 6, lane = tid & 63;
    const int lquad = lane >> 4, lcol = lane & 15;
    const int bh = b * NUM_HEADS + h;

    // gather + shuffle + cvt: Xs[i][q*5+c] = src[b, s0+i, c*256 + h*16 + q]
    #pragma unroll
    for (int it = 0; it < 40; it++) {
        int idx = tid + it * 256;
        int i = idx / 80, rem = idx % 80, c = rem >> 4, q = rem & 15;
        float v = src[(size_t)(b * SEQ + s0 + i) * D_MODEL + c * 256 + h * 16 + q];
        Xs[i * 104 + q * 5 + c] = f2b(v);
    }
    // zero pad d = 80..95
    {
        int i = tid >> 1, half = tid & 1;
        *(uint4*)(Xs + i * 104 + 80 + half * 8) = make_uint4(0, 0, 0, 0);
    }
    __syncthreads();

    // X fragments: rows wave*32 + mt*16 + lcol (identical layout for A or B use)
    short8 xf[2][3];
    #pragma unroll
    for (int mt = 0; mt < 2; mt++)
        #pragma unroll
        for (int ks = 0; ks < 3; ks++)
            xf[mt][ks] = *(const short8*)(Xs + (wave*32 + mt*16 + lcol)*104 + ks*32 + lquad*8);

    const bf16* Wh = Wcat + (size_t)h * 240 * 96;
    const float qscale = 1.4426950408889634f * 0.11180339887498949f;

    // ---- Q and K: D[token][e] ----
    #pragma unroll
    for (int mat = 0; mat < 2; mat++) {
        const bf16* Wm = Wh + mat * 80 * 96;
        short8 wf[5][3];
        #pragma unroll
        for (int n = 0; n < 5; n++)
            #pragma unroll
            for (int ks = 0; ks < 3; ks++)
                wf[n][ks] = *(const short8*)(Wm + (n*16 + lcol)*96 + ks*32 + lquad*8);

        f32x4 acc[2][5];
        #pragma unroll
        for (int mt = 0; mt < 2; mt++)
            #pragma unroll
            for (int n = 0; n < 5; n++)
                #pragma unroll
                for (int r = 0; r < 4; r++) acc[mt][n][r] = 0.f;

        #pragma unroll
        for (int ks = 0; ks < 3; ks++)
            #pragma unroll
            for (int n = 0; n < 5; n++) {
                acc[0][n] = MFMA16(xf[0][ks], wf[n][ks], acc[0][n]);
                acc[1][n] = MFMA16(xf[1][ks], wf[n][ks], acc[1][n]);
            }

        const float* bias = (mat == 0) ? bq : bk;
        bf16* Out = (mat == 0) ? Qb : Kb;
        const float scale = (mat == 0) ? qscale : 1.f;
        #pragma unroll
        for (int n = 0; n < 5; n++) {
            float bb = bias[h * 80 + n * 16 + lcol];
            #pragma unroll
            for (int mt = 0; mt < 2; mt++)
                #pragma unroll
                for (int r = 0; r < 4; r++) {
                    int srow = s0 + wave*32 + mt*16 + lquad*4 + r;
                    Out[((size_t)bh * SEQ + srow) * DP + n*16 + lcol] =
                        f2b((acc[mt][n][r] + bb) * scale);
                }
        }
    }
    // zero pad e = 80..95 for Q and K (one row per thread-pair)
    {
        int i = tid >> 1, half = tid & 1;
        size_t row = ((size_t)bh * SEQ + s0 + i) * DP + 80 + half * 8;
        *(uint4*)(Qb + row) = make_uint4(0, 0, 0, 0);
        *(uint4*)(Kb + row) = make_uint4(0, 0, 0, 0);
    }

    // ---- V: D[e][token] (A=W rows=e, B=X rows=token) ----
    {
        const bf16* Wm = Wh + 2 * 80 * 96;
        short8 wf[5][3];
        #pragma unroll
        for (int m = 0; m < 5; m++)
            #pragma unroll
            for (int ks = 0; ks < 3; ks++)
                wf[m][ks] = *(const short8*)(Wm + (m*16 + lcol)*96 + ks*32 + lquad*8);

        f32x4 acc[5][2];
        #pragma unroll
        for (int m = 0; m < 5; m++)
            #pragma unroll
            for (int nt = 0; nt < 2; nt++)
                #pragma unroll
                for (int r = 0; r < 4; r++) acc[m][nt][r] = 0.f;

        #pragma unroll
        for (int ks = 0; ks < 3; ks++)
            #pragma unroll
            for (int m = 0; m < 5; m++) {
                acc[m][0] = MFMA16(wf[m][ks], xf[0][ks], acc[m][0]);
                acc[m][1] = MFMA16(wf[m][ks], xf[1][ks], acc[m][1]);
            }

        #pragma unroll
        for (int m = 0; m < 5; m++) {
            float4 bb4 = *(const float4*)(bv + h * 80 + m * 16 + lquad * 4);
            float bb[4] = {bb4.x, bb4.y, bb4.z, bb4.w};
            #pragma unroll
            for (int nt = 0; nt < 2; nt++)
                #pragma unroll
                for (int r = 0; r < 4; r++) {
                    int e = m*16 + lquad*4 + r;
                    int token = s0 + wave*32 + nt*16 + lcol;
                    Vg[((size_t)bh * D_K + e) * SEQ + token] =
                        f2b(acc[m][nt][r] + bb[r]);
                }
        }
    }
}

// ---------------------------------------------------------------------------
// Kernel 2: MFMA flash attention. grid (S/128, BH), 256 threads = 4 waves.
// S^T = K·Q^T; softmax stats via in-lane reduce + shfl_xor(16,32);
// P -> LDS (A-layout) -> PV with V^T tile. Q LDS reused as P region.
// ---------------------------------------------------------------------------
__global__ __launch_bounds__(256) void attn_kernel(
    const bf16* __restrict__ Qb, const bf16* __restrict__ Kb,
    const bf16* __restrict__ Vg, bf16* __restrict__ Cc)
{
    __shared__ char smem[48384];          // Qs/P 24576 | Ks 12288 | Vt 11520
    bf16* Qs = (bf16*)smem;
    bf16* Ks = (bf16*)(smem + 24576);
    bf16* Vt = (bf16*)(smem + 36864);

    const int tid = threadIdx.x;
    const int wave = tid >> 6, lane = tid & 63;
    const int lquad = lane >> 4, lcol = lane & 15;
    const int bh = blockIdx.y;
    const int b = bh >> 4, h = bh & 15;
    const int q0 = blockIdx.x * 128;

    {
        const uint4* sg = (const uint4*)(Qb + (size_t)(bh * SEQ + q0) * DP);
        uint4* dl = (uint4*)Qs;
        #pragma unroll
        for (int i = 0; i < 6; i++) dl[tid + i * 256] = sg[tid + i * 256];
    }
    __syncthreads();

    short8 qf[2][3];
    #pragma unroll
    for (int nt = 0; nt < 2; nt++)
        #pragma unroll
        for (int ks = 0; ks < 3; ks++)
            qf[nt][ks] = *(const short8*)(Qs + (wave*32 + nt*16 + lcol)*DP + ks*32 + lquad*8);

    f32x4 Oacc[2][5];
    #pragma unroll
    for (int mt = 0; mt < 2; mt++)
        #pragma unroll
        for (int ne = 0; ne < 5; ne++)
            #pragma unroll
            for (int r = 0; r < 4; r++) Oacc[mt][ne][r] = 0.f;

    float m[2] = {-1e30f, -1e30f}, l[2] = {0.f, 0.f};
    bf16* Pw = (bf16*)(smem + wave * 4608);

    for (int kt = 0; kt < 16; kt++) {
        __syncthreads();
        {
            const uint4* sg = (const uint4*)(Kb + (size_t)(bh * SEQ + kt * 64) * DP);
            uint4* dl = (uint4*)Ks;
            #pragma unroll
            for (int i = 0; i < 3; i++) dl[tid + i * 256] = sg[tid + i * 256];
        }
        #pragma unroll
        for (int i = 0; i < 3; i++) {
            int idx = tid + i * 256;
            if (idx < 640) {
                int e = idx >> 3, c = idx & 7;
                *(uint4*)(Vt + e * 72 + c * 8) =
                    *(const uint4*)(Vg + ((size_t)(bh * D_K + e) << 10) + kt * 64 + c * 8);
            }
        }
        __syncthreads();

        f32x4 st[4][2];
        #pragma unroll
        for (int mt = 0; mt < 4; mt++)
            #pragma unroll
            for (int nt = 0; nt < 2; nt++)
                #pragma unroll
                for (int r = 0; r < 4; r++) st[mt][nt][r] = 0.f;

        #pragma unroll
        for (int ks = 0; ks < 3; ks++) {
            #pragma unroll
            for (int mt = 0; mt < 4; mt++) {
                short8 af = *(const short8*)(Ks + (mt*16 + lcol)*DP + ks*32 + lquad*8);
                st[mt][0] = MFMA16(af, qf[0][ks], st[mt][0]);
                st[mt][1] = MFMA16(af, qf[1][ks], st[mt][1]);
            }
        }

        float a[2];
        #pragma unroll
        for (int nt = 0; nt < 2; nt++) {
            float mx = st[0][nt][0];
            #pragma unroll
            for (int mt = 0; mt < 4; mt++)
                #pragma unroll
                for (int r = 0; r < 4; r++) mx = fmaxf(mx, st[mt][nt][r]);
            mx = fmaxf(mx, __shfl_xor(mx, 16));
            mx = fmaxf(mx, __shfl_xor(mx, 32));
            float mn = fmaxf(m[nt], mx);
            a[nt] = exp2f(m[nt] - mn);
            m[nt] = mn;
            float s = 0.f;
            #pragma unroll
            for (int mt = 0; mt < 4; mt++)
                #pragma unroll
                for (int r = 0; r < 4; r++) {
                    float p = exp2f(st[mt][nt][r] - mn);
                    s += p;
                    Pw[(nt*16 + lcol)*72 + mt*16 + lquad*4 + r] = f2b(p);
                }
            s += __shfl_xor(s, 16);
            s += __shfl_xor(s, 32);
            l[nt] = l[nt] * a[nt] + s;
        }

        #pragma unroll
        for (int mt = 0; mt < 2; mt++) {
            f32x4 aq;
            #pragma unroll
            for (int r = 0; r < 4; r++)
                aq[r] = __shfl(a[mt], (lane & 48) | (lquad*4 + r));
            #pragma unroll
            for (int ne = 0; ne < 5; ne++)
                #pragma unroll
                for (int r = 0; r < 4; r++) Oacc[mt][ne][r] *= aq[r];
        }

        #pragma unroll
        for (int js = 0; js < 2; js++) {
            short8 pf[2];
            #pragma unroll
            for (int mt = 0; mt < 2; mt++)
                pf[mt] = *(const short8*)(Pw + (mt*16 + lcol)*72 + js*32 + lquad*8);
            #pragma unroll
            for (int ne = 0; ne < 5; ne++) {
                short8 vf = *(const short8*)(Vt + (ne*16 + lcol)*72 + js*32 + lquad*8);
                Oacc[0][ne] = MFMA16(pf[0], vf, Oacc[0][ne]);
                Oacc[1][ne] = MFMA16(pf[1], vf, Oacc[1][ne]);
            }
        }
    }

    float inv[2] = {1.f / l[0], 1.f / l[1]};
    #pragma unroll
    for (int mt = 0; mt < 2; mt++) {
        f32x4 li;
        #pragma unroll
        for (int r = 0; r < 4; r++)
            li[r] = __shfl(inv[mt], (lane & 48) | (lquad*4 + r));
        #pragma unroll
        for (int ne = 0; ne < 5; ne++)
            #pragma unroll
            for (int r = 0; r < 4; r++) {
                int s_row = q0 + wave*32 + mt*16 + lquad*4 + r;
                int e = ne*16 + lcol;
                Cc[(size_t)(b * SEQ + s_row) * D_MODEL + h * D_K + e] =
                    f2b(Oacc[mt][ne][r] * li[r]);
            }
    }
}

// ---------------------------------------------------------------------------
// Kernel 3: output projection out = Cc @ Wo^T + bo via MFMA (m97 pattern).
// ---------------------------------------------------------------------------
__global__ __launch_bounds__(256) void proj_kernel(
    const bf16* __restrict__ Cc, const bf16* __restrict__ Wb,
    const float* __restrict__ bo, float* __restrict__ out)
{
    __shared__ bf16 As[128 * 72];
    __shared__ bf16 Bs[128 * 72];
    const int tid = threadIdx.x;
    const int wave = tid >> 6, lane = tid & 63;
    const int lquad = lane >> 4, lcol = lane & 15;
    const int t0 = blockIdx.x * 128, o0 = blockIdx.y * 128;
    const int mrow = (wave & 1) * 64, ncol = (wave >> 1) * 64;

    f32x4 acc[4][4];
    #pragma unroll
    for (int mt = 0; mt < 4; mt++)
        #pragma unroll
        for (int nt = 0; nt < 4; nt++)
            #pragma unroll
            for (int r = 0; r < 4; r++) acc[mt][nt][r] = 0.f;

    for (int kc = 0; kc < 20; kc++) {
        __syncthreads();
        #pragma unroll
        for (int i = 0; i < 4; i++) {
            int idx = tid + i * 256;
            int r = idx >> 3, c = idx & 7;
            *(uint4*)(As + r * 72 + c * 8) =
                *(const uint4*)(Cc + (size_t)(t0 + r) * D_MODEL + kc * 64 + c * 8);
            *(uint4*)(Bs + r * 72 + c * 8) =
                *(const uint4*)(Wb + (size_t)(o0 + r) * D_MODEL + kc * 64 + c * 8);
        }
        __syncthreads();
        #pragma unroll
        for (int ks = 0; ks < 2; ks++) {
            short8 am[4], bn[4];
            #pragma unroll
            for (int t = 0; t < 4; t++) {
                am[t] = *(const short8*)(As + (mrow + t*16 + lcol)*72 + ks*32 + lquad*8);
                bn[t] = *(const short8*)(Bs + (ncol + t*16 + lcol)*72 + ks*32 + lquad*8);
            }
            #pragma unroll
            for (int mt = 0; mt < 4; mt++)
                #pragma unroll
                for (int nt = 0; nt < 4; nt++)
                    acc[mt][nt] = MFMA16(am[mt], bn[nt], acc[mt][nt]);
        }
    }

    #pragma unroll
    for (int nt = 0; nt < 4; nt++) {
        float bias = bo[o0 + ncol + nt*16 + lcol];
        #pragma unroll
        for (int mt = 0; mt < 4; mt++)
            #pragma unroll
            for (int r = 0; r < 4; r++)
                out[(size_t)(t0 + mrow + mt*16 + lquad*4 + r) * D_MODEL
                    + o0 + ncol + nt*16 + lcol] = acc[mt][nt][r] + bias;
    }
}

// ---------------------------------------------------------------------------
extern "C" void kernel_launch(void* const* d_in, const int* in_sizes, int n_in,
                              void* d_out, int out_size, void* d_ws, size_t ws_size,
                              hipStream_t stream) {
    const float* src = (const float*)d_in[0];
    const float* Wq = (const float*)d_in[3];
    const float* bq = (const float*)d_in[4];
    const float* Wk = (const float*)d_in[5];
    const float* bk = (const float*)d_in[6];
    const float* Wv = (const float*)d_in[7];
    const float* bv = (const float*)d_in[8];
    const float* Wo = (const float*)d_in[9];
    const float* bo = (const float*)d_in[10];
    float* out = (float*)d_out;

    // ws layout (bytes):
    //   Qb bf16 [BH][S][96]    @ 0         12,582,912
    //   Kb bf16 [BH][S][96]    @ 12582912  12,582,912
    //   Vg bf16 [BH][80][S]    @ 25165824  10,485,760
    //   Cc bf16 [B][S][1280]   @ 35651584  10,485,760  (also Wcat before attn)
    //   Wb bf16 [1280][1280]   @ 46137344   3,276,800
    // Wcat bf16 [16][240][96] overlaps Cc: cvtw -> qkv(read) -> attn(clobber). Safe.
    char* ws = (char*)d_ws;
    bf16* Qb = (bf16*)(ws);
    bf16* Kb = (bf16*)(ws + (size_t)12582912);
    bf16* Vg = (bf16*)(ws + (size_t)25165824);
    bf16* Cc = (bf16*)(ws + (size_t)35651584);
    bf16* Wcat = (bf16*)(ws + (size_t)35651584);
    bf16* Wb = (bf16*)(ws + (size_t)46137344);

    cvtw_kernel<<<dim3(1440), 256, 0, stream>>>(Wq, Wk, Wv, Wcat);
    cvt_kernel<<<dim3(D_MODEL * D_MODEL / 1024), 256, 0, stream>>>(Wo, Wb);
    qkv_kernel<<<dim3(BATCH * SEQ / 128, NUM_HEADS), 256, 0, stream>>>(
        src, bq, bk, bv, Wcat, Qb, Kb, Vg);
    attn_kernel<<<dim3(SEQ / 128, BH), 256, 0, stream>>>(Qb, Kb, Vg, Cc);
    proj_kernel<<<dim3(SEQ * BATCH / 128, D_MODEL / 128), 256, 0, stream>>>(
        Cc, Wb, bo, out);
}